// Round 4
// 56.363 us; speedup vs baseline: 1.0039x; 1.0039x over previous
//
#include <hip/hip_runtime.h>
#include <stdint.h>

typedef float f32x4 __attribute__((ext_vector_type(4)));
typedef float f32x2 __attribute__((ext_vector_type(2)));
typedef unsigned int u32x4 __attribute__((ext_vector_type(4)));

// LDS layout: 40096 B -> 4 blocks/CU (<=40960)
#define XP_OFF   0        // x bf16 packed [128][256B] swizzled; scores overlay after B2
#define RE_OFF   32768    // SoA: rot0,rot1,rot2,ent0,ent1,ent2 -- 6 x 128 floats
#define QV_OFF   35840    // f32x4[128] (q0,q1,q2,0)
#define KV_OFF   37888    // SoA: k0,k1,k2 -- 3 x 128 floats
#define WRED_OFF 39424    // 4 waves x 8 floats
#define CORN_OFF 39552
#define CONV_OFF 39568
#define INV_OFF  39584    // float[128] per-row 1/den
#define LDS_TOTAL 40096

__device__ __forceinline__ int rowswz(int row) {
  return ((row & 7) << 4) ^ (((row >> 3) & 1) << 6);
}
__device__ __forceinline__ f32x2 pk_fma(f32x2 a, f32x2 b, f32x2 c) {
  f32x2 d;
  asm("v_pk_fma_f32 %0, %1, %2, %3" : "=v"(d) : "v"(a), "v"(b), "v"(c));
  return d;
}
__device__ __forceinline__ f32x2 pk_add(f32x2 a, f32x2 b) {
  f32x2 d;
  asm("v_pk_add_f32 %0, %1, %2" : "=v"(d) : "v"(a), "v"(b));
  return d;
}
__device__ __forceinline__ f32x2 pk_mul(f32x2 a, f32x2 b) {
  f32x2 d;
  asm("v_pk_mul_f32 %0, %1, %2" : "=v"(d) : "v"(a), "v"(b));
  return d;
}
__device__ __forceinline__ uint32_t cvtpk(float lo, float hi) {
  uint32_t r;
  asm("v_cvt_pk_bf16_f32 %0, %1, %2" : "=v"(r) : "v"(lo), "v"(hi));
  return r;
}

// Structure: exact round-0 baseline (proven: passes incl. replay, 56.6us).
// Persistent-loop / cross-batch prefetch variants (R1-R3) all failed harness
// checks with timing-dependent corruption despite barrier-airtight LDS graphs;
// that line is abandoned. Only delta vs round 0: cw/cb loads hoisted to the
// prologue (value-proven in R2's passing check-488 path) so thread 0 does not
// serialize a cold global load inside phase 2 while 255 threads wait at B3.

__global__ __launch_bounds__(256, 4)
void hsa_fused(const float* __restrict__ xall,
               const float* __restrict__ rotp,
               const float* __restrict__ entp,
               const float* __restrict__ cw,
               const float* __restrict__ cb,
               float* __restrict__ out) {
  __shared__ __align__(16) char lds[LDS_TOTAL];
  float* wred  = (float*)(lds + WRED_OFF);
  float* corn  = (float*)(lds + CORN_OFF);
  float* convo = (float*)(lds + CONV_OFF);
  float* invar = (float*)(lds + INV_OFF);

  const int t   = threadIdx.x;
  const int wv  = t >> 6;
  const int l   = t & 63;
  const int lo  = l & 15;
  const int hi  = (l >> 4) & 3;
  const int r32 = l & 31;
  const int mh  = l >> 5;
  const int r   = t >> 1;        // staging/proj row
  const int h   = t & 1;         // staging/proj half
  const int b   = blockIdx.x;
  const float* xg = xall + (size_t)b * (128 * 128);

  // ---------- phase 0: global row loads; bf16 cvt_pk -> swizzled LDS ----------
  f32x4 tl[16];                   // my half-row of x (64 floats)
  {
    const f32x4* xrow4 = (const f32x4*)(xg + r * 128 + h * 64);
#pragma unroll
    for (int i = 0; i < 16; ++i) tl[i] = xrow4[i];
  }
  if (t < 128) {                  // rot/ent -> SoA component arrays
    float* re = (float*)(lds + RE_OFF);
    re[t]        = rotp[3*t];   re[t + 128]  = rotp[3*t+1]; re[t + 256]  = rotp[3*t+2];
    re[t + 384]  = entp[3*t];   re[t + 512]  = entp[3*t+1]; re[t + 640]  = entp[3*t+2];
  }
  // conv params: issued here so the loads overlap phases 0-1 instead of
  // stalling thread 0 inside phase 2 (hoist proven correct in R2@488).
  const f32x4 cwv = *(const f32x4*)cw;
  const float cbv = cb[0];
  {
    const int swr = rowswz(r);
    char* xrow = lds + XP_OFF + r * 256;
#pragma unroll
    for (int q = 0; q < 8; ++q) {
      u32x4 w;
      w[0] = cvtpk(tl[2*q][0],   tl[2*q][1]);
      w[1] = cvtpk(tl[2*q][2],   tl[2*q][3]);
      w[2] = cvtpk(tl[2*q+1][0], tl[2*q+1][1]);
      w[3] = cvtpk(tl[2*q+1][2], tl[2*q+1][3]);
      *(u32x4*)(xrow + ((h * 128 + q * 16) ^ swr)) = w;
    }
  }
  __syncthreads();   // B1: x(bf16) + rot/ent staged

  // ---------- phase 1: packed-fp32 projections + conv partials ----------
  f32x2 q0p={0.f,0.f}, q1p={0.f,0.f}, q2p={0.f,0.f};
  f32x2 k0p={0.f,0.f}, k1p={0.f,0.f}, k2p={0.f,0.f}, rsp={0.f,0.f};
  {
    const char* reb = lds + RE_OFF + h * 256;
#pragma unroll
    for (int s = 0; s < 16; ++s) {
      f32x4 r0 = *(const f32x4*)(reb + 0*512 + s*16);
      f32x4 r1 = *(const f32x4*)(reb + 1*512 + s*16);
      f32x4 r2 = *(const f32x4*)(reb + 2*512 + s*16);
      f32x4 e0 = *(const f32x4*)(reb + 3*512 + s*16);
      f32x4 e1 = *(const f32x4*)(reb + 4*512 + s*16);
      f32x4 e2 = *(const f32x4*)(reb + 5*512 + s*16);
      f32x4 xv = tl[s];
      f32x2 xlo = {xv[0], xv[1]}, xhi = {xv[2], xv[3]};
      q0p = pk_fma(xlo, (f32x2){r0[0],r0[1]}, q0p);
      q1p = pk_fma(xlo, (f32x2){r1[0],r1[1]}, q1p);
      q2p = pk_fma(xlo, (f32x2){r2[0],r2[1]}, q2p);
      k0p = pk_fma(xlo, (f32x2){e0[0],e0[1]}, k0p);
      k1p = pk_fma(xlo, (f32x2){e1[0],e1[1]}, k1p);
      k2p = pk_fma(xlo, (f32x2){e2[0],e2[1]}, k2p);
      rsp = pk_add(rsp, xlo);
      q0p = pk_fma(xhi, (f32x2){r0[2],r0[3]}, q0p);
      q1p = pk_fma(xhi, (f32x2){r1[2],r1[3]}, q1p);
      q2p = pk_fma(xhi, (f32x2){r2[2],r2[3]}, q2p);
      k0p = pk_fma(xhi, (f32x2){e0[2],e0[3]}, k0p);
      k1p = pk_fma(xhi, (f32x2){e1[2],e1[3]}, k1p);
      k2p = pk_fma(xhi, (f32x2){e2[2],e2[3]}, k2p);
      rsp = pk_add(rsp, xhi);
    }
  }
  float q0 = q0p[0]+q0p[1], q1 = q1p[0]+q1p[1], q2 = q2p[0]+q2p[1];
  float k0 = k0p[0]+k0p[1], k1 = k1p[0]+k1p[1], k2 = k2p[0]+k2p[1];
  float rs = rsp[0]+rsp[1];
  q0 += __shfl_xor(q0, 1); q1 += __shfl_xor(q1, 1); q2 += __shfl_xor(q2, 1);
  k0 += __shfl_xor(k0, 1); k1 += __shfl_xor(k1, 1); k2 += __shfl_xor(k2, 1);
  if (h == 0) {
    ((f32x4*)(lds + QV_OFF))[r] = (f32x4){q0, q1, q2, 0.f};
  } else {
    float* kv = (float*)(lds + KV_OFF);
    kv[r] = k0; kv[r + 128] = k1; kv[r + 256] = k2;
  }

  {
    float pA  = rs;
    float pR0 = (r == 0)   ? rs : 0.f;
    float pRL = (r == 127) ? rs : 0.f;
    float pC0 = (h == 0) ? tl[0][0]  : 0.f;
    float pCL = (h == 1) ? tl[15][3] : 0.f;
#pragma unroll
    for (int s = 32; s > 0; s >>= 1) {
      pA  += __shfl_xor(pA,  s);
      pR0 += __shfl_xor(pR0, s);
      pRL += __shfl_xor(pRL, s);
      pC0 += __shfl_xor(pC0, s);
      pCL += __shfl_xor(pCL, s);
    }
    if (l == 0) {
      wred[wv*8+0]=pA; wred[wv*8+1]=pR0; wred[wv*8+2]=pRL;
      wred[wv*8+3]=pC0; wred[wv*8+4]=pCL;
    }
    if (t == 0)   corn[0] = tl[0][0];    // x[0][0]
    if (t == 1)   corn[1] = tl[15][3];   // x[0][127]
    if (t == 254) corn[2] = tl[0][0];    // x[127][0]
    if (t == 255) corn[3] = tl[15][3];   // x[127][127]
  }

  // B-fragments from LDS (after proj so tl can die; v_perm repack)
  u32x4 bfrag[2][4];               // frag n: col wv*32 + 2*lo + n
#pragma unroll
  for (int kt = 0; kt < 4; ++kt)
#pragma unroll
    for (int m = 0; m < 4; ++m) {
      const int k = kt * 32 + 8 * hi + 2 * m;
      const int rawb = wv * 64 + lo * 4;
      uint32_t A  = *(const uint32_t*)(lds + XP_OFF + k * 256 + (rawb ^ rowswz(k)));
      uint32_t Bv = *(const uint32_t*)(lds + XP_OFF + (k + 1) * 256 + (rawb ^ rowswz(k + 1)));
      bfrag[0][kt][m] = __builtin_amdgcn_perm(Bv, A, 0x05040100u); // lo16(A)|lo16(B)<<16
      bfrag[1][kt][m] = __builtin_amdgcn_perm(Bv, A, 0x07060302u); // hi16(A)|hi16(B)<<16
    }
  __syncthreads();   // B2: qv/kv/wred ready; x-LDS dead

  // ---------- phase 2: conv scalar + softmax (unnormalized e -> bf16 scores) ----------
  if (t == 0) {
    float A  = wred[0]+wred[8]+wred[16]+wred[24];
    float R0 = wred[1]+wred[9]+wred[17]+wred[25];
    float RL = wred[2]+wred[10]+wred[18]+wred[26];
    float C0 = wred[3]+wred[11]+wred[19]+wred[27];
    float CL = wred[4]+wred[12]+wred[20]+wred[28];
    float S00 = A - RL - CL + corn[3];
    float S01 = A - RL - C0 + corn[2];
    float S10 = A - R0 - CL + corn[1];
    float S11 = A - R0 - C0 + corn[0];
    *convo = cbv + (cwv[0]*S00 + cwv[1]*S01 + cwv[2]*S10 + cwv[3]*S11) * (1.0f/16129.0f);
  }

  const int row = wv * 32 + r32;
  {
    f32x4 qrow = ((const f32x4*)(lds + QV_OFF))[row];
    f32x2 qq0 = {qrow[0], qrow[0]};
    f32x2 qq1 = {qrow[1], qrow[1]};
    f32x2 qq2 = {qrow[2], qrow[2]};
    const f32x2 m1   = {-1.f, -1.f};
    const f32x2 nl2e = {-1.4426950408889634f, -1.4426950408889634f};
    const f32x2 pl2e = { 1.4426950408889634f,  1.4426950408889634f};
    const char* kb = lds + KV_OFF;
    uint32_t wbuf[32];
    f32x2 denp = {0.f, 0.f};
#pragma unroll
    for (int i4 = 0; i4 < 16; ++i4) {
      const int m0 = mh * 64 + i4 * 4;
      f32x4 k0q = *(const f32x4*)(kb + 0    + m0 * 4);
      f32x4 k1q = *(const f32x4*)(kb + 512  + m0 * 4);
      f32x4 k2q = *(const f32x4*)(kb + 1024 + m0 * 4);
#pragma unroll
      for (int p = 0; p < 2; ++p) {
        f32x2 kp0 = {k0q[2*p], k0q[2*p+1]};
        f32x2 kp1 = {k1q[2*p], k1q[2*p+1]};
        f32x2 kp2 = {k2q[2*p], k2q[2*p+1]};
        f32x2 d0 = pk_fma(kp0, m1, qq0);
        f32x2 d1 = pk_fma(kp1, m1, qq1);
        f32x2 d2 = pk_fma(kp2, m1, qq2);
        f32x2 dist = pk_mul(d0, d0);
        dist = pk_fma(d1, d1, dist);
        dist = pk_fma(d2, d2, dist);
        f32x2 tt = pk_mul(dist, nl2e);          // -dist*log2e
        f32x2 sim = {exp2f(tt[0]), exp2f(tt[1])};
        f32x2 uu = pk_mul(sim, pl2e);           // sim*log2e
        f32x2 ev = {exp2f(uu[0]), exp2f(uu[1])};
        denp = pk_add(denp, ev);
        wbuf[i4*2 + p] = cvtpk(ev[0], ev[1]);
      }
    }
    float den = denp[0] + denp[1];
    den += __shfl_xor(den, 32);
    float inv = 1.0f / den;
    if (mh == 0) invar[row] = inv;

    char* srow = lds + XP_OFF + row * 256;
    const int sw = rowswz(row);
#pragma unroll
    for (int u = 0; u < 8; ++u) {
      u32x4 w = { wbuf[u*4+0], wbuf[u*4+1], wbuf[u*4+2], wbuf[u*4+3] };
      *(u32x4*)(srow + ((mh * 128 + u * 16) ^ sw)) = w;
    }
  }
  __syncthreads();   // B3: scores + inv ready

  // ---------- phase 3: PV via MFMA ----------
  f32x4 acc[8][2];
#pragma unroll
  for (int mt = 0; mt < 8; ++mt)
#pragma unroll
    for (int n = 0; n < 2; ++n) acc[mt][n] = (f32x4){0.f,0.f,0.f,0.f};

#pragma unroll
  for (int mt = 0; mt < 8; ++mt) {
    const int arow = mt * 16 + lo;
    const char* ab = lds + XP_OFF + arow * 256;
    const int sw2 = rowswz(arow);
    u32x4 a0 = *(const u32x4*)(ab + ((0   + hi * 16) ^ sw2));
    u32x4 a1 = *(const u32x4*)(ab + ((64  + hi * 16) ^ sw2));
    u32x4 a2 = *(const u32x4*)(ab + ((128 + hi * 16) ^ sw2));
    u32x4 a3 = *(const u32x4*)(ab + ((192 + hi * 16) ^ sw2));
#pragma unroll
    for (int n = 0; n < 2; ++n) {
      asm volatile("v_mfma_f32_16x16x32_bf16 %0, %1, %2, %0"
                   : "+v"(acc[mt][n]) : "v"(a0), "v"(bfrag[n][0]));
      asm volatile("v_mfma_f32_16x16x32_bf16 %0, %1, %2, %0"
                   : "+v"(acc[mt][n]) : "v"(a1), "v"(bfrag[n][1]));
      asm volatile("v_mfma_f32_16x16x32_bf16 %0, %1, %2, %0"
                   : "+v"(acc[mt][n]) : "v"(a2), "v"(bfrag[n][2]));
      asm volatile("v_mfma_f32_16x16x32_bf16 %0, %1, %2, %0"
                   : "+v"(acc[mt][n]) : "v"(a3), "v"(bfrag[n][3]));
    }
  }
  asm volatile("s_nop 7\n\ts_nop 7"
               : "+v"(acc[0][0]), "+v"(acc[0][1]), "+v"(acc[1][0]), "+v"(acc[1][1]),
                 "+v"(acc[2][0]), "+v"(acc[2][1]), "+v"(acc[3][0]), "+v"(acc[3][1]),
                 "+v"(acc[4][0]), "+v"(acc[4][1]), "+v"(acc[5][0]), "+v"(acc[5][1]),
                 "+v"(acc[6][0]), "+v"(acc[6][1]), "+v"(acc[7][0]), "+v"(acc[7][1]));

  // ---------- epilogue: out = acc*inv_row + conv ----------
  {
    float co = *convo;
    float* outb = out + (size_t)b * (128 * 128);
#pragma unroll
    for (int mt = 0; mt < 8; ++mt) {
      f32x4 invq = *(const f32x4*)(lds + INV_OFF + (mt * 16 + 4 * hi) * 4);
#pragma unroll
      for (int rr = 0; rr < 4; ++rr) {
        int rowg = mt * 16 + 4 * hi + rr;
        float2 v;
        v.x = fmaf(acc[mt][0][rr], invq[rr], co);   // col 2*lo
        v.y = fmaf(acc[mt][1][rr], invq[rr], co);   // col 2*lo+1
        *(float2*)(outb + rowg * 128 + wv * 32 + 2 * lo) = v;
      }
    }
  }
}

extern "C" void kernel_launch(void* const* d_in, const int* in_sizes, int n_in,
                              void* d_out, int out_size, void* d_ws, size_t ws_size,
                              hipStream_t stream) {
  const float* x    = (const float*)d_in[0];
  const float* rotp = (const float*)d_in[1];
  const float* entp = (const float*)d_in[2];
  const float* cw   = (const float*)d_in[3];
  const float* cb   = (const float*)d_in[4];
  float* out = (float*)d_out;
  int B = in_sizes[0] >> 14;
  hipLaunchKernelGGL(hsa_fused, dim3(B), dim3(256), 0, stream,
                     x, rotp, entp, cw, cb, out);
}

// Round 6
// 53.478 us; speedup vs baseline: 1.0581x; 1.0540x over previous
//
#include <hip/hip_runtime.h>
#include <stdint.h>

typedef float f32x4 __attribute__((ext_vector_type(4)));
typedef float f32x2 __attribute__((ext_vector_type(2)));
typedef unsigned int u32x4 __attribute__((ext_vector_type(4)));

// LDS layout: 40096 B -> 4 blocks/CU (<=40960)
#define XP_OFF   0        // x bf16 packed [128][256B] swizzled; scores overlay after B2
#define RE_OFF   32768    // SoA: rot0,rot1,rot2,ent0,ent1,ent2 -- 6 x 128 floats
#define QV_OFF   35840    // f32x4[128] (q0,q1,q2,0)
#define KV_OFF   37888    // SoA: k0,k1,k2 -- 3 x 128 floats
#define WRED_OFF 39424    // 4 waves x 8 floats
#define CORN_OFF 39552
#define CONV_OFF 39568
#define INV_OFF  39584    // float[128] per-row 1/den
#define LDS_TOTAL 40096

__device__ __forceinline__ int rowswz(int row) {
  return ((row & 7) << 4) ^ (((row >> 3) & 1) << 6);
}
__device__ __forceinline__ f32x2 pk_fma(f32x2 a, f32x2 b, f32x2 c) {
  f32x2 d;
  asm("v_pk_fma_f32 %0, %1, %2, %3" : "=v"(d) : "v"(a), "v"(b), "v"(c));
  return d;
}
__device__ __forceinline__ f32x2 pk_add(f32x2 a, f32x2 b) {
  f32x2 d;
  asm("v_pk_add_f32 %0, %1, %2" : "=v"(d) : "v"(a), "v"(b));
  return d;
}
__device__ __forceinline__ f32x2 pk_mul(f32x2 a, f32x2 b) {
  f32x2 d;
  asm("v_pk_mul_f32 %0, %1, %2" : "=v"(d) : "v"(a), "v"(b));
  return d;
}
__device__ __forceinline__ uint32_t cvtpk(float lo, float hi) {
  uint32_t r;
  asm("v_cvt_pk_bf16_f32 %0, %1, %2" : "=v"(r) : "v"(lo), "v"(hi));
  return r;
}

// Structure: exact round-4 green kernel (proven: passes incl. replay, 56.36us).
// Only delta: epilogue stores are NON-TEMPORAL (via ext_vector f32x2 -- HIP's
// float2 class is not a valid __builtin_nontemporal_store operand, R5 compile
// fail). Output (134MB) is written once, never re-read; letting it allocate in
// L2/L3 evicts ~half of x from the 256MB Infinity Cache each launch (observed:
// FETCH_SIZE 66MB vs 134MB input). nt stores keep L3 for x. Zero sync change.

__global__ __launch_bounds__(256, 4)
void hsa_fused(const float* __restrict__ xall,
               const float* __restrict__ rotp,
               const float* __restrict__ entp,
               const float* __restrict__ cw,
               const float* __restrict__ cb,
               float* __restrict__ out) {
  __shared__ __align__(16) char lds[LDS_TOTAL];
  float* wred  = (float*)(lds + WRED_OFF);
  float* corn  = (float*)(lds + CORN_OFF);
  float* convo = (float*)(lds + CONV_OFF);
  float* invar = (float*)(lds + INV_OFF);

  const int t   = threadIdx.x;
  const int wv  = t >> 6;
  const int l   = t & 63;
  const int lo  = l & 15;
  const int hi  = (l >> 4) & 3;
  const int r32 = l & 31;
  const int mh  = l >> 5;
  const int r   = t >> 1;        // staging/proj row
  const int h   = t & 1;         // staging/proj half
  const int b   = blockIdx.x;
  const float* xg = xall + (size_t)b * (128 * 128);

  // ---------- phase 0: global row loads; bf16 cvt_pk -> swizzled LDS ----------
  f32x4 tl[16];                   // my half-row of x (64 floats)
  {
    const f32x4* xrow4 = (const f32x4*)(xg + r * 128 + h * 64);
#pragma unroll
    for (int i = 0; i < 16; ++i) tl[i] = xrow4[i];
  }
  if (t < 128) {                  // rot/ent -> SoA component arrays
    float* re = (float*)(lds + RE_OFF);
    re[t]        = rotp[3*t];   re[t + 128]  = rotp[3*t+1]; re[t + 256]  = rotp[3*t+2];
    re[t + 384]  = entp[3*t];   re[t + 512]  = entp[3*t+1]; re[t + 640]  = entp[3*t+2];
  }
  // conv params: issued here so the loads overlap phases 0-1 instead of
  // stalling thread 0 inside phase 2.
  const f32x4 cwv = *(const f32x4*)cw;
  const float cbv = cb[0];
  {
    const int swr = rowswz(r);
    char* xrow = lds + XP_OFF + r * 256;
#pragma unroll
    for (int q = 0; q < 8; ++q) {
      u32x4 w;
      w[0] = cvtpk(tl[2*q][0],   tl[2*q][1]);
      w[1] = cvtpk(tl[2*q][2],   tl[2*q][3]);
      w[2] = cvtpk(tl[2*q+1][0], tl[2*q+1][1]);
      w[3] = cvtpk(tl[2*q+1][2], tl[2*q+1][3]);
      *(u32x4*)(xrow + ((h * 128 + q * 16) ^ swr)) = w;
    }
  }
  __syncthreads();   // B1: x(bf16) + rot/ent staged

  // ---------- phase 1: packed-fp32 projections + conv partials ----------
  f32x2 q0p={0.f,0.f}, q1p={0.f,0.f}, q2p={0.f,0.f};
  f32x2 k0p={0.f,0.f}, k1p={0.f,0.f}, k2p={0.f,0.f}, rsp={0.f,0.f};
  {
    const char* reb = lds + RE_OFF + h * 256;
#pragma unroll
    for (int s = 0; s < 16; ++s) {
      f32x4 r0 = *(const f32x4*)(reb + 0*512 + s*16);
      f32x4 r1 = *(const f32x4*)(reb + 1*512 + s*16);
      f32x4 r2 = *(const f32x4*)(reb + 2*512 + s*16);
      f32x4 e0 = *(const f32x4*)(reb + 3*512 + s*16);
      f32x4 e1 = *(const f32x4*)(reb + 4*512 + s*16);
      f32x4 e2 = *(const f32x4*)(reb + 5*512 + s*16);
      f32x4 xv = tl[s];
      f32x2 xlo = {xv[0], xv[1]}, xhi = {xv[2], xv[3]};
      q0p = pk_fma(xlo, (f32x2){r0[0],r0[1]}, q0p);
      q1p = pk_fma(xlo, (f32x2){r1[0],r1[1]}, q1p);
      q2p = pk_fma(xlo, (f32x2){r2[0],r2[1]}, q2p);
      k0p = pk_fma(xlo, (f32x2){e0[0],e0[1]}, k0p);
      k1p = pk_fma(xlo, (f32x2){e1[0],e1[1]}, k1p);
      k2p = pk_fma(xlo, (f32x2){e2[0],e2[1]}, k2p);
      rsp = pk_add(rsp, xlo);
      q0p = pk_fma(xhi, (f32x2){r0[2],r0[3]}, q0p);
      q1p = pk_fma(xhi, (f32x2){r1[2],r1[3]}, q1p);
      q2p = pk_fma(xhi, (f32x2){r2[2],r2[3]}, q2p);
      k0p = pk_fma(xhi, (f32x2){e0[2],e0[3]}, k0p);
      k1p = pk_fma(xhi, (f32x2){e1[2],e1[3]}, k1p);
      k2p = pk_fma(xhi, (f32x2){e2[2],e2[3]}, k2p);
      rsp = pk_add(rsp, xhi);
    }
  }
  float q0 = q0p[0]+q0p[1], q1 = q1p[0]+q1p[1], q2 = q2p[0]+q2p[1];
  float k0 = k0p[0]+k0p[1], k1 = k1p[0]+k1p[1], k2 = k2p[0]+k2p[1];
  float rs = rsp[0]+rsp[1];
  q0 += __shfl_xor(q0, 1); q1 += __shfl_xor(q1, 1); q2 += __shfl_xor(q2, 1);
  k0 += __shfl_xor(k0, 1); k1 += __shfl_xor(k1, 1); k2 += __shfl_xor(k2, 1);
  if (h == 0) {
    ((f32x4*)(lds + QV_OFF))[r] = (f32x4){q0, q1, q2, 0.f};
  } else {
    float* kv = (float*)(lds + KV_OFF);
    kv[r] = k0; kv[r + 128] = k1; kv[r + 256] = k2;
  }

  {
    float pA  = rs;
    float pR0 = (r == 0)   ? rs : 0.f;
    float pRL = (r == 127) ? rs : 0.f;
    float pC0 = (h == 0) ? tl[0][0]  : 0.f;
    float pCL = (h == 1) ? tl[15][3] : 0.f;
#pragma unroll
    for (int s = 32; s > 0; s >>= 1) {
      pA  += __shfl_xor(pA,  s);
      pR0 += __shfl_xor(pR0, s);
      pRL += __shfl_xor(pRL, s);
      pC0 += __shfl_xor(pC0, s);
      pCL += __shfl_xor(pCL, s);
    }
    if (l == 0) {
      wred[wv*8+0]=pA; wred[wv*8+1]=pR0; wred[wv*8+2]=pRL;
      wred[wv*8+3]=pC0; wred[wv*8+4]=pCL;
    }
    if (t == 0)   corn[0] = tl[0][0];    // x[0][0]
    if (t == 1)   corn[1] = tl[15][3];   // x[0][127]
    if (t == 254) corn[2] = tl[0][0];    // x[127][0]
    if (t == 255) corn[3] = tl[15][3];   // x[127][127]
  }

  // B-fragments from LDS (after proj so tl can die; v_perm repack)
  u32x4 bfrag[2][4];               // frag n: col wv*32 + 2*lo + n
#pragma unroll
  for (int kt = 0; kt < 4; ++kt)
#pragma unroll
    for (int m = 0; m < 4; ++m) {
      const int k = kt * 32 + 8 * hi + 2 * m;
      const int rawb = wv * 64 + lo * 4;
      uint32_t A  = *(const uint32_t*)(lds + XP_OFF + k * 256 + (rawb ^ rowswz(k)));
      uint32_t Bv = *(const uint32_t*)(lds + XP_OFF + (k + 1) * 256 + (rawb ^ rowswz(k + 1)));
      bfrag[0][kt][m] = __builtin_amdgcn_perm(Bv, A, 0x05040100u); // lo16(A)|lo16(B)<<16
      bfrag[1][kt][m] = __builtin_amdgcn_perm(Bv, A, 0x07060302u); // hi16(A)|hi16(B)<<16
    }
  __syncthreads();   // B2: qv/kv/wred ready; x-LDS dead

  // ---------- phase 2: conv scalar + softmax (unnormalized e -> bf16 scores) ----------
  if (t == 0) {
    float A  = wred[0]+wred[8]+wred[16]+wred[24];
    float R0 = wred[1]+wred[9]+wred[17]+wred[25];
    float RL = wred[2]+wred[10]+wred[18]+wred[26];
    float C0 = wred[3]+wred[11]+wred[19]+wred[27];
    float CL = wred[4]+wred[12]+wred[20]+wred[28];
    float S00 = A - RL - CL + corn[3];
    float S01 = A - RL - C0 + corn[2];
    float S10 = A - R0 - CL + corn[1];
    float S11 = A - R0 - C0 + corn[0];
    *convo = cbv + (cwv[0]*S00 + cwv[1]*S01 + cwv[2]*S10 + cwv[3]*S11) * (1.0f/16129.0f);
  }

  const int row = wv * 32 + r32;
  {
    f32x4 qrow = ((const f32x4*)(lds + QV_OFF))[row];
    f32x2 qq0 = {qrow[0], qrow[0]};
    f32x2 qq1 = {qrow[1], qrow[1]};
    f32x2 qq2 = {qrow[2], qrow[2]};
    const f32x2 m1   = {-1.f, -1.f};
    const f32x2 nl2e = {-1.4426950408889634f, -1.4426950408889634f};
    const f32x2 pl2e = { 1.4426950408889634f,  1.4426950408889634f};
    const char* kb = lds + KV_OFF;
    uint32_t wbuf[32];
    f32x2 denp = {0.f, 0.f};
#pragma unroll
    for (int i4 = 0; i4 < 16; ++i4) {
      const int m0 = mh * 64 + i4 * 4;
      f32x4 k0q = *(const f32x4*)(kb + 0    + m0 * 4);
      f32x4 k1q = *(const f32x4*)(kb + 512  + m0 * 4);
      f32x4 k2q = *(const f32x4*)(kb + 1024 + m0 * 4);
#pragma unroll
      for (int p = 0; p < 2; ++p) {
        f32x2 kp0 = {k0q[2*p], k0q[2*p+1]};
        f32x2 kp1 = {k1q[2*p], k1q[2*p+1]};
        f32x2 kp2 = {k2q[2*p], k2q[2*p+1]};
        f32x2 d0 = pk_fma(kp0, m1, qq0);
        f32x2 d1 = pk_fma(kp1, m1, qq1);
        f32x2 d2 = pk_fma(kp2, m1, qq2);
        f32x2 dist = pk_mul(d0, d0);
        dist = pk_fma(d1, d1, dist);
        dist = pk_fma(d2, d2, dist);
        f32x2 tt = pk_mul(dist, nl2e);          // -dist*log2e
        f32x2 sim = {exp2f(tt[0]), exp2f(tt[1])};
        f32x2 uu = pk_mul(sim, pl2e);           // sim*log2e
        f32x2 ev = {exp2f(uu[0]), exp2f(uu[1])};
        denp = pk_add(denp, ev);
        wbuf[i4*2 + p] = cvtpk(ev[0], ev[1]);
      }
    }
    float den = denp[0] + denp[1];
    den += __shfl_xor(den, 32);
    float inv = 1.0f / den;
    if (mh == 0) invar[row] = inv;

    char* srow = lds + XP_OFF + row * 256;
    const int sw = rowswz(row);
#pragma unroll
    for (int u = 0; u < 8; ++u) {
      u32x4 w = { wbuf[u*4+0], wbuf[u*4+1], wbuf[u*4+2], wbuf[u*4+3] };
      *(u32x4*)(srow + ((mh * 128 + u * 16) ^ sw)) = w;
    }
  }
  __syncthreads();   // B3: scores + inv ready

  // ---------- phase 3: PV via MFMA ----------
  f32x4 acc[8][2];
#pragma unroll
  for (int mt = 0; mt < 8; ++mt)
#pragma unroll
    for (int n = 0; n < 2; ++n) acc[mt][n] = (f32x4){0.f,0.f,0.f,0.f};

#pragma unroll
  for (int mt = 0; mt < 8; ++mt) {
    const int arow = mt * 16 + lo;
    const char* ab = lds + XP_OFF + arow * 256;
    const int sw2 = rowswz(arow);
    u32x4 a0 = *(const u32x4*)(ab + ((0   + hi * 16) ^ sw2));
    u32x4 a1 = *(const u32x4*)(ab + ((64  + hi * 16) ^ sw2));
    u32x4 a2 = *(const u32x4*)(ab + ((128 + hi * 16) ^ sw2));
    u32x4 a3 = *(const u32x4*)(ab + ((192 + hi * 16) ^ sw2));
#pragma unroll
    for (int n = 0; n < 2; ++n) {
      asm volatile("v_mfma_f32_16x16x32_bf16 %0, %1, %2, %0"
                   : "+v"(acc[mt][n]) : "v"(a0), "v"(bfrag[n][0]));
      asm volatile("v_mfma_f32_16x16x32_bf16 %0, %1, %2, %0"
                   : "+v"(acc[mt][n]) : "v"(a1), "v"(bfrag[n][1]));
      asm volatile("v_mfma_f32_16x16x32_bf16 %0, %1, %2, %0"
                   : "+v"(acc[mt][n]) : "v"(a2), "v"(bfrag[n][2]));
      asm volatile("v_mfma_f32_16x16x32_bf16 %0, %1, %2, %0"
                   : "+v"(acc[mt][n]) : "v"(a3), "v"(bfrag[n][3]));
    }
  }
  asm volatile("s_nop 7\n\ts_nop 7"
               : "+v"(acc[0][0]), "+v"(acc[0][1]), "+v"(acc[1][0]), "+v"(acc[1][1]),
                 "+v"(acc[2][0]), "+v"(acc[2][1]), "+v"(acc[3][0]), "+v"(acc[3][1]),
                 "+v"(acc[4][0]), "+v"(acc[4][1]), "+v"(acc[5][0]), "+v"(acc[5][1]),
                 "+v"(acc[6][0]), "+v"(acc[6][1]), "+v"(acc[7][0]), "+v"(acc[7][1]));

  // ---------- epilogue: out = acc*inv_row + conv (non-temporal stores) ----------
  {
    float co = *convo;
    float* outb = out + (size_t)b * (128 * 128);
#pragma unroll
    for (int mt = 0; mt < 8; ++mt) {
      f32x4 invq = *(const f32x4*)(lds + INV_OFF + (mt * 16 + 4 * hi) * 4);
#pragma unroll
      for (int rr = 0; rr < 4; ++rr) {
        int rowg = mt * 16 + 4 * hi + rr;
        f32x2 v;
        v[0] = fmaf(acc[mt][0][rr], invq[rr], co);   // col 2*lo
        v[1] = fmaf(acc[mt][1][rr], invq[rr], co);   // col 2*lo+1
        __builtin_nontemporal_store(v, (f32x2*)(outb + rowg * 128 + wv * 32 + 2 * lo));
      }
    }
  }
}

extern "C" void kernel_launch(void* const* d_in, const int* in_sizes, int n_in,
                              void* d_out, int out_size, void* d_ws, size_t ws_size,
                              hipStream_t stream) {
  const float* x    = (const float*)d_in[0];
  const float* rotp = (const float*)d_in[1];
  const float* entp = (const float*)d_in[2];
  const float* cw   = (const float*)d_in[3];
  const float* cb   = (const float*)d_in[4];
  float* out = (float*)d_out;
  int B = in_sizes[0] >> 14;
  hipLaunchKernelGGL(hsa_fused, dim3(B), dim3(256), 0, stream,
                     x, rotp, entp, cw, cb, out);
}